// Round 5
// baseline (1358.481 us; speedup 1.0000x reference)
//
#include <hip/hip_runtime.h>
#include <math.h>

#define B 128
#define H 32
#define D 128
#define S 64
#define T0 32
#define SCALE 0.125f

#define NB 2            // (b,h) pairs per WG (same head)
#define NT 512
#define KVS 132         // K/V row stride (floats): 16B aligned

// padded interleaved layouts (conflict-free broadcast reads)
#define X2IDX(d,p) ((((d)>>5)*66) + (((d)&31)<<1) + (p))      // [4][32][2] stride-66
#define QPIDX(p,d) ((p)*160 + (((d)>>4)*20) + ((d)&15))       // [2][8][16+4pad]

#define SZ_KV  (NB*S*KVS)                 // 16896 floats
#define OFF_KL 0
#define OFF_VL (OFF_KL + SZ_KV)
#define OFF_X2 (OFF_VL + SZ_KV)           // 264 floats
#define OFF_QP (OFF_X2 + 264)             // 320 floats
#define OFF_XO (OFF_QP + 320)             // 264 floats
#define OFF_SC (OFF_XO + 264)             // 128 floats
#define LDS_FLOATS (OFF_SC + 128)
#define LDS_BYTES (LDS_FLOATS*4)          // 139,072 B

__global__ void __launch_bounds__(NT, 2)
attn_decode_kernel(const float* __restrict__ x_in,
                   const float* __restrict__ k_in,
                   const float* __restrict__ v_in,
                   const float* __restrict__ wq,
                   const float* __restrict__ wk,
                   const float* __restrict__ wv,
                   const float* __restrict__ wo,
                   float* __restrict__ out)
{
    extern __shared__ float smem[];
    float* Kl = smem + OFF_KL;
    float* Vl = smem + OFF_VL;
    float* x2 = smem + OFF_X2;
    float* qp = smem + OFF_QP;
    float* xo = smem + OFF_XO;
    float* sc = smem + OFF_SC;

    const int tid = threadIdx.x;
    const int w = tid >> 6;               // wave 0..7
    const int l = tid & 63;               // lane
    // XCD swizzle: contiguous 256-WG chunk per XCD -> 4 heads' weights per L2
    const int blk = (blockIdx.x & 7) * 256 + (blockIdx.x >> 3);
    const int h  = blk >> 6;
    const int b0 = (blk & 63) << 1;

    // uniform ownership: every thread owns quarter-depth x 1 column of all 4 matrices
    const int colw = w*16 + (l & 15);     // 8 waves x 16 cols = 128
    const int qd   = l >> 4;              // depth quarter 0..3

    // ---- one-time weight loads (128 floats/thread, static-indexed) ----
    float wq_r[32], wk_r[32], wv_r[32], wo_r[32];
    {
        const size_t wbase = (size_t)h*D*D + (size_t)(qd*32)*D + colw;
        const float* bq = wq + wbase;
        const float* bk = wk + wbase;
        const float* bv = wv + wbase;
        const float* bo = wo + wbase;
        #pragma unroll
        for (int i = 0; i < 32; ++i) {
            wq_r[i] = bq[i*D];
            wk_r[i] = bk[i*D];
            wv_r[i] = bv[i*D];
            wo_r[i] = bo[i*D];
        }
    }

    // ---- stage K/V + x into LDS ----
    for (int i = tid; i < NB*S*(D/4); i += NT) {
        int p = i >> 11, s = (i >> 5) & 63, g = i & 31;
        size_t base = (size_t)((b0+p)*H + h) * S * D;
        float4 k4 = reinterpret_cast<const float4*>(k_in + base)[s*32 + g];
        float4 v4 = reinterpret_cast<const float4*>(v_in + base)[s*32 + g];
        *reinterpret_cast<float4*>(&Kl[(p*S + s)*KVS + g*4]) = k4;
        *reinterpret_cast<float4*>(&Vl[(p*S + s)*KVS + g*4]) = v4;
    }
    if (tid < 256) {
        int p = tid >> 7, d = tid & 127;
        x2[X2IDX(d,p)] = x_in[(size_t)((b0+p)*H + h)*D + d];
    }
    __syncthreads();

    const int s2 = w*8 + (l & 7);                 // P2: score row
    const int e8 = l >> 3;                        // P2: depth eighth
    const int p4 = w >> 2;                        // P4: pair
    const int colb = ((w & 3) << 5) + (l & 31);   // P4: column
    const int sh = l >> 5;                        // P4: s-half

    for (int t = T0; t < S; ++t) {
        // ================= P1: QKV projections (direct write) =================
        {
            float aq0=0.f, aq1=0.f, ak0=0.f, ak1=0.f, av0=0.f, av1=0.f;
            #pragma unroll
            for (int i = 0; i < 32; ++i) {
                float2 xv = *reinterpret_cast<const float2*>(&x2[qd*66 + (i<<1)]);
                float wqi = wq_r[i], wki = wk_r[i], wvi = wv_r[i];
                aq0 = fmaf(xv.x, wqi, aq0); aq1 = fmaf(xv.y, wqi, aq1);
                ak0 = fmaf(xv.x, wki, ak0); ak1 = fmaf(xv.y, wki, ak1);
                av0 = fmaf(xv.x, wvi, av0); av1 = fmaf(xv.y, wvi, av1);
            }
            // combine depth quarters intra-wave (lane = qd*16 + col16)
            aq0 += __shfl_xor(aq0,16); aq0 += __shfl_xor(aq0,32);
            aq1 += __shfl_xor(aq1,16); aq1 += __shfl_xor(aq1,32);
            ak0 += __shfl_xor(ak0,16); ak0 += __shfl_xor(ak0,32);
            ak1 += __shfl_xor(ak1,16); ak1 += __shfl_xor(ak1,32);
            av0 += __shfl_xor(av0,16); av0 += __shfl_xor(av0,32);
            av1 += __shfl_xor(av1,16); av1 += __shfl_xor(av1,32);
            if (l < 16) {
                qp[QPIDX(0,colw)] = aq0 * SCALE;      // fold softmax scale into q
                qp[QPIDX(1,colw)] = aq1 * SCALE;
                Kl[(0*S + t)*KVS + colw] = ak0;       // scatter row t
                Kl[(1*S + t)*KVS + colw] = ak1;
                Vl[(0*S + t)*KVS + colw] = av0;
                Vl[(1*S + t)*KVS + colw] = av1;
            }
        }
        __syncthreads();

        // ================= P2: scores q.K^T (all waves) =================
        {
            float sA = 0.f, sB = 0.f;
            #pragma unroll
            for (int j = 0; j < 4; ++j) {
                float4 q0 = *reinterpret_cast<const float4*>(&qp[0*160 + e8*20 + j*4]);
                float4 k0 = *reinterpret_cast<const float4*>(&Kl[(0*S + s2)*KVS + e8*16 + j*4]);
                sA = fmaf(q0.x,k0.x, fmaf(q0.y,k0.y, fmaf(q0.z,k0.z, fmaf(q0.w,k0.w, sA))));
                float4 q1 = *reinterpret_cast<const float4*>(&qp[1*160 + e8*20 + j*4]);
                float4 k1 = *reinterpret_cast<const float4*>(&Kl[(1*S + s2)*KVS + e8*16 + j*4]);
                sB = fmaf(q1.x,k1.x, fmaf(q1.y,k1.y, fmaf(q1.z,k1.z, fmaf(q1.w,k1.w, sB))));
            }
            // combine depth eighths (lane = e8*8 + s8)
            sA += __shfl_xor(sA,8); sA += __shfl_xor(sA,16); sA += __shfl_xor(sA,32);
            sB += __shfl_xor(sB,8); sB += __shfl_xor(sB,16); sB += __shfl_xor(sB,32);
            if (l < 8) {
                float2 scv; scv.x = sA; scv.y = sB;
                *reinterpret_cast<float2*>(&sc[s2 << 1]) = scv;
            }
        }
        __syncthreads();

        // ========== P4: softmax (in-wave, redundant per wave) + PV ==========
        {
            float a = sc[(l << 1) + p4];
            float mx = a;
            #pragma unroll
            for (int msk = 1; msk < 64; msk <<= 1) mx = fmaxf(mx, __shfl_xor(mx, msk));
            float e = expf(a - mx);
            float Z = e;
            #pragma unroll
            for (int msk = 1; msk < 64; msk <<= 1) Z += __shfl_xor(Z, msk);
            float acc = 0.f;
            const float* Vrow = &Vl[(p4*S + (sh<<5))*KVS + colb];
            #pragma unroll
            for (int i = 0; i < 32; ++i) {
                float es = __shfl(e, (sh<<5) + i);    // broadcast e_s from owning lane
                acc = fmaf(es, Vrow[i*KVS], acc);
            }
            acc += __shfl_xor(acc, 32);               // combine s-halves
            if (l < 32) xo[X2IDX(colb, p4)] = acc / Z;
        }
        __syncthreads();

        // ================= P5: O projection (direct write) =================
        {
            float o0 = 0.f, o1 = 0.f;
            #pragma unroll
            for (int i = 0; i < 32; ++i) {
                float2 xv = *reinterpret_cast<const float2*>(&xo[qd*66 + (i<<1)]);
                o0 = fmaf(xv.x, wo_r[i], o0);
                o1 = fmaf(xv.y, wo_r[i], o1);
            }
            o0 += __shfl_xor(o0,16); o0 += __shfl_xor(o0,32);
            o1 += __shfl_xor(o1,16); o1 += __shfl_xor(o1,32);
            if (l < 16) {
                float2 xn; xn.x = o0; xn.y = o1;
                *reinterpret_cast<float2*>(&x2[((colw>>5)*66) + ((colw&31)<<1)]) = xn;
            }
        }
        __syncthreads();
    }

    // ---- outputs: k cache, v cache, final x ----
    float* kout = out;
    float* vout = out + (size_t)B*H*S*D;
    float* xout = out + (size_t)2*B*H*S*D;
    for (int i = tid; i < NB*S*(D/4); i += NT) {
        int p = i >> 11, s = (i >> 5) & 63, g = i & 31;
        size_t base = (size_t)((b0+p)*H + h) * S * D;
        float4 k4 = *reinterpret_cast<const float4*>(&Kl[(p*S + s)*KVS + g*4]);
        float4 v4 = *reinterpret_cast<const float4*>(&Vl[(p*S + s)*KVS + g*4]);
        reinterpret_cast<float4*>(kout + base)[s*32 + g] = k4;
        reinterpret_cast<float4*>(vout + base)[s*32 + g] = v4;
    }
    if (tid < 256) {
        int p = tid >> 7, d = tid & 127;
        xout[(size_t)((b0+p)*H + h)*D + d] = x2[X2IDX(d,p)];
    }
}

extern "C" void kernel_launch(void* const* d_in, const int* in_sizes, int n_in,
                              void* d_out, int out_size, void* d_ws, size_t ws_size,
                              hipStream_t stream) {
    (void)in_sizes; (void)n_in; (void)out_size; (void)d_ws; (void)ws_size;
    const float* x  = (const float*)d_in[0];
    const float* k  = (const float*)d_in[1];
    const float* v  = (const float*)d_in[2];
    const float* wq = (const float*)d_in[3];
    const float* wk = (const float*)d_in[4];
    const float* wv = (const float*)d_in[5];
    const float* wo = (const float*)d_in[6];
    float* out = (float*)d_out;

    hipFuncSetAttribute(reinterpret_cast<const void*>(attn_decode_kernel),
                        hipFuncAttributeMaxDynamicSharedMemorySize, LDS_BYTES);

    dim3 grid(B*H/NB);   // 2048 WGs
    dim3 block(NT);
    attn_decode_kernel<<<grid, block, LDS_BYTES, stream>>>(x, k, v, wq, wk, wv, wo, out);
}